// Round 5
// baseline (187.251 us; speedup 1.0000x reference)
//
#include <hip/hip_runtime.h>

#define IN_F 128
#define HC 32            // edge chunks
#define HR 4             // node ranges (range hist fits in LDS)
#define RSIZE_MAX 12544  // >= ceil(nN/HR) for nN=50000

typedef __attribute__((ext_vector_type(8))) short bf16x8;
typedef __attribute__((ext_vector_type(4))) float f32x4;

static __device__ __forceinline__ unsigned short f2bf(float x) {
    unsigned u = __float_as_uint(x);
    unsigned r = (u + 0x7FFFu + ((u >> 16) & 1u)) >> 16;
    return (unsigned short)r;
}
static __device__ __forceinline__ float bf2f(unsigned short u) {
    return __uint_as_float(((unsigned)u) << 16);
}

// ---------------- privatized histogram: no global atomics ----------------
__global__ __launch_bounds__(256) void k_hist(const int* __restrict__ src,
                                              const int* __restrict__ dst,
                                              int* __restrict__ part,
                                              int nN, int nE) {
    __shared__ int h[RSIZE_MAX];
    const int bid  = blockIdx.x;
    const int kind = bid / (HR * HC);
    const int rem  = bid % (HR * HC);
    const int r    = rem / HC;
    const int c    = rem % HC;
    const int rs   = (nN + HR - 1) / HR;
    const int rbeg = r * rs;
    const int rsize = min(rs, nN - rbeg);
    if (rsize <= 0) return;

    const int* key = kind ? dst : src;

    for (int i = threadIdx.x; i < rsize; i += 256) h[i] = 0;
    __syncthreads();

    const int chunk = (nE + HC - 1) / HC;
    const int ebeg = c * chunk;
    const int eend = min(ebeg + chunk, nE);

    for (int i = ebeg + threadIdx.x * 4; i < eend; i += 256 * 4) {
        if (i + 3 < eend) {
            const int4 k4 = *reinterpret_cast<const int4*>(key + i);
            int a;
            a = k4.x - rbeg; if ((unsigned)a < (unsigned)rsize) atomicAdd(&h[a], 1);
            a = k4.y - rbeg; if ((unsigned)a < (unsigned)rsize) atomicAdd(&h[a], 1);
            a = k4.z - rbeg; if ((unsigned)a < (unsigned)rsize) atomicAdd(&h[a], 1);
            a = k4.w - rbeg; if ((unsigned)a < (unsigned)rsize) atomicAdd(&h[a], 1);
        } else {
            for (int j = i; j < eend; ++j) {
                int a = key[j] - rbeg;
                if ((unsigned)a < (unsigned)rsize) atomicAdd(&h[a], 1);
            }
        }
    }
    __syncthreads();

    int* pout = part + ((size_t)kind * HC + c) * nN + rbeg;
    for (int i = threadIdx.x; i < rsize; i += 256) pout[i] = h[i];
}

// ---------------- merge: deg_out->dinv_out; dst partials -> per-chunk prefixes ----
// part[HC + c][n] becomes chunkoff[c][n] = sum_{c'<c} count; cnt_in[n] = total.
__global__ void k_merge(int* __restrict__ part, int* __restrict__ cnt_in,
                        float* __restrict__ dinv_out, float* __restrict__ dinv_in,
                        int nN) {
    const int n = blockIdx.x * blockDim.x + threadIdx.x;
    if (n >= nN) return;
    int s = 0;
#pragma unroll 4
    for (int c = 0; c < HC; ++c) s += part[(size_t)c * nN + n];
    int run = 0;
#pragma unroll 4
    for (int c = 0; c < HC; ++c) {
        const size_t idx = ((size_t)HC + c) * nN + n;
        int v = part[idx];
        part[idx] = run;
        run += v;
    }
    cnt_in[n]   = run;
    dinv_out[n] = rsqrtf(fmaxf((float)s, 1.0f));
    dinv_in[n]  = rsqrtf(fmaxf((float)run, 1.0f));
}

// ---------------- hierarchical exclusive scan: cnt_in -> offs ----------------
__global__ __launch_bounds__(256) void k_scan_blk(const int* __restrict__ cnt,
                                                  int* __restrict__ offs,
                                                  int* __restrict__ part, int nN) {
    __shared__ int ts[256];
    const int t = threadIdx.x;
    const int base = blockIdx.x * 1024 + t * 4;
    int4 v = make_int4(0, 0, 0, 0);
    if (base + 3 < nN) {
        v = *reinterpret_cast<const int4*>(cnt + base);
    } else {
        if (base + 0 < nN) v.x = cnt[base + 0];
        if (base + 1 < nN) v.y = cnt[base + 1];
        if (base + 2 < nN) v.z = cnt[base + 2];
        if (base + 3 < nN) v.w = cnt[base + 3];
    }
    const int s = v.x + v.y + v.z + v.w;
    ts[t] = s;
    __syncthreads();
    for (int d = 1; d < 256; d <<= 1) {
        int u = (t >= d) ? ts[t - d] : 0;
        __syncthreads();
        ts[t] += u;
        __syncthreads();
    }
    const int ex = ts[t] - s;
    if (t == 255) part[blockIdx.x] = ts[255];
    int4 o;
    o.x = ex;
    o.y = o.x + v.x;
    o.z = o.y + v.y;
    o.w = o.z + v.z;
    if (base + 3 < nN) {
        *reinterpret_cast<int4*>(offs + base) = o;
    } else {
        if (base + 0 < nN) offs[base + 0] = o.x;
        if (base + 1 < nN) offs[base + 1] = o.y;
        if (base + 2 < nN) offs[base + 2] = o.z;
        if (base + 3 < nN) offs[base + 3] = o.w;
    }
}

__global__ __launch_bounds__(256) void k_scan_top(int* __restrict__ part, int nb) {
    __shared__ int ts[256];
    const int t = threadIdx.x;
    const int v = (t < nb) ? part[t] : 0;
    ts[t] = v;
    __syncthreads();
    for (int d = 1; d < 256; d <<= 1) {
        int u = (t >= d) ? ts[t - d] : 0;
        __syncthreads();
        ts[t] += u;
        __syncthreads();
    }
    if (t < nb) part[t] = ts[t] - v;
}

__global__ __launch_bounds__(256) void k_scan_add(int* __restrict__ offs,
                                                  const int* __restrict__ part,
                                                  int nN, int nE) {
    const int base = blockIdx.x * 1024 + threadIdx.x * 4;
    const int add = part[blockIdx.x];
    if (base + 3 < nN) {
        int4 o = *reinterpret_cast<int4*>(offs + base);
        o.x += add; o.y += add; o.z += add; o.w += add;
        *reinterpret_cast<int4*>(offs + base) = o;
    } else {
#pragma unroll
        for (int j = 0; j < 4; ++j)
            if (base + j < nN) offs[base + j] += add;
    }
    if (blockIdx.x == 0 && threadIdx.x == 0) offs[nN] = nE;
}

// ---------------- h[n] = bf16(feat[n] * dinv_out[n]) ----------------
__global__ __launch_bounds__(256) void k_scale(const float* __restrict__ feat,
                                               const float* __restrict__ dinv,
                                               unsigned short* __restrict__ h, int nN) {
    const int i = blockIdx.x * 256 + threadIdx.x;  // one thread = 4 elems
    if (i >= nN * (IN_F / 4)) return;
    const int node = i >> 5;
    const int j = (i & 31) * 4;
    const float s = dinv[node];
    const float4 v = *reinterpret_cast<const float4*>(feat + (size_t)node * IN_F + j);
    ushort4 o;
    o.x = f2bf(v.x * s);
    o.y = f2bf(v.y * s);
    o.z = f2bf(v.z * s);
    o.w = f2bf(v.w * s);
    *reinterpret_cast<ushort4*>(h + (size_t)node * IN_F + j) = o;
}

// ---------------- Wt[j][k] = bf16(W[k][j]) (single block) ----------------
__global__ __launch_bounds__(256) void k_wprep(const float* __restrict__ W,
                                               unsigned short* __restrict__ wt) {
    __shared__ float wl[128 * 128];
    for (int i = threadIdx.x * 4; i < 128 * 128; i += 256 * 4)
        *reinterpret_cast<float4*>(&wl[i]) = *reinterpret_cast<const float4*>(&W[i]);
    __syncthreads();
    const int col = threadIdx.x >> 1;
    const int k0  = (threadIdx.x & 1) * 64;
    for (int k = k0; k < k0 + 64; ++k)
        wt[col * 128 + k] = f2bf(wl[k * 128 + col]);
}

// ---------------- bucket edges by dst via LDS cursors (no global atomics) ----
__global__ __launch_bounds__(256) void k_bin2(const int* __restrict__ src,
                                              const int* __restrict__ dst,
                                              const int* __restrict__ offs,
                                              const int* __restrict__ chunkoff,
                                              int* __restrict__ eidx, int nN, int nE) {
    __shared__ int cur[RSIZE_MAX];
    const int bid = blockIdx.x;
    const int r = bid / HC;
    const int c = bid % HC;
    const int rs = (nN + HR - 1) / HR;
    const int rbeg = r * rs;
    const int rsize = min(rs, nN - rbeg);
    if (rsize <= 0) return;

    for (int i = threadIdx.x; i < rsize; i += 256)
        cur[i] = offs[rbeg + i] + chunkoff[(size_t)c * nN + rbeg + i];
    __syncthreads();

    const int chunk = (nE + HC - 1) / HC;
    const int ebeg = c * chunk;
    const int eend = min(ebeg + chunk, nE);
    for (int i = ebeg + threadIdx.x; i < eend; i += 256) {
        const int d = dst[i] - rbeg;
        if ((unsigned)d < (unsigned)rsize) {
            const int p = atomicAdd(&cur[d], 1);
            eidx[p] = src[i];
        }
    }
}

// ---------------- gather: agg[d] = bf16( sum_{e in bin(d)} h[src_e] ) ----------
// one wave per node; lane owns 2 feats (bf16x2 = 4B load).
__global__ __launch_bounds__(256) void k_gather(
    const unsigned short* __restrict__ h, const int* __restrict__ eidx,
    const int* __restrict__ offs, unsigned short* __restrict__ agg, int nN) {
    const int node = blockIdx.x * 4 + (threadIdx.x >> 6);
    if (node >= nN) return;
    const int lane = threadIdx.x & 63;
    const int beg = offs[node], end = offs[node + 1];

    float ax = 0.0f, ay = 0.0f;
    for (int base = beg; base < end; base += 64) {
        int n = end - base;
        if (n > 64) n = 64;
        int s_l = 0;
        if (lane < n) s_l = eidx[base + lane];
        for (int i = 0; i < n; ++i) {
            const int s = __shfl(s_l, i);
            const unsigned v = *reinterpret_cast<const unsigned*>(h + (size_t)s * IN_F + lane * 2);
            ax += __uint_as_float(v << 16);
            ay += __uint_as_float(v & 0xFFFF0000u);
        }
    }
    unsigned o = ((unsigned)f2bf(ay) << 16) | (unsigned)f2bf(ax);
    *reinterpret_cast<unsigned*>(agg + (size_t)node * IN_F + lane * 2) = o;
}

// ---------------- out = (agg @ W) * dinv_in[:,None] + bias  (bf16 MFMA) -------
// block = 4 waves, 64 rows; wave = 16 rows x 128 cols (8 tiles), K=128 in 4 steps.
__global__ __launch_bounds__(256) void k_gemm(
    const unsigned short* __restrict__ agg, const unsigned short* __restrict__ wt,
    const float* __restrict__ bias, const float* __restrict__ dinv_in,
    float* __restrict__ out, int nN) {
    const int lane = threadIdx.x & 63;
    const int wave = threadIdx.x >> 6;
    const int r0 = blockIdx.x * 64 + wave * 16;
    const int rA = min(r0 + (lane & 15), nN - 1);       // A-frag row (clamped)
    const int g = lane >> 4;                            // k-group

    // dinv for the 4 C-rows this lane writes
    float di[4];
#pragma unroll
    for (int q = 0; q < 4; ++q) {
        int rr = r0 + g * 4 + q;
        di[q] = dinv_in[min(rr, nN - 1)];
    }

    f32x4 acc[8];
#pragma unroll
    for (int t = 0; t < 8; ++t) acc[t] = (f32x4){0.f, 0.f, 0.f, 0.f};

#pragma unroll
    for (int s = 0; s < 4; ++s) {
        const bf16x8 a = *reinterpret_cast<const bf16x8*>(agg + (size_t)rA * IN_F + s * 32 + g * 8);
#pragma unroll
        for (int t = 0; t < 8; ++t) {
            const int col = t * 16 + (lane & 15);
            const bf16x8 b = *reinterpret_cast<const bf16x8*>(wt + (size_t)col * IN_F + s * 32 + g * 8);
            acc[t] = __builtin_amdgcn_mfma_f32_16x16x32_bf16(a, b, acc[t], 0, 0, 0);
        }
    }

#pragma unroll
    for (int t = 0; t < 8; ++t) {
        const int col = t * 16 + (lane & 15);
        const float bv = bias[col];
#pragma unroll
        for (int q = 0; q < 4; ++q) {
            const int rr = r0 + g * 4 + q;
            if (rr < nN)
                out[(size_t)rr * IN_F + col] = acc[t][q] * di[q] + bv;
        }
    }
}

extern "C" void kernel_launch(void* const* d_in, const int* in_sizes, int n_in,
                              void* d_out, int out_size, void* d_ws, size_t ws_size,
                              hipStream_t stream) {
    const float* feat = (const float*)d_in[0];
    const int*   src  = (const int*)d_in[1];
    const int*   dst  = (const int*)d_in[2];
    const float* W    = (const float*)d_in[3];
    const float* bias = (const float*)d_in[4];
    float*       out  = (float*)d_out;

    const int nE = in_sizes[1];
    const int nN = in_sizes[0] / IN_F;
    const int nb = (nN + 1023) / 1024;

    // workspace layout (bytes):
    //  [0, 12.8M)   part [2][HC][nN] ints  -> later agg bf16 [nN][128] (alias)
    //  [12.8M, ..)  h bf16 [nN][128]       12.8M
    //  then eidx[nE], wt[128*128] bf16, cnt_in[nN], dinv_out[nN], dinv_in[nN],
    //  offs[nN+1], partscan[256]
    char* base = (char*)d_ws;
    int*            part_h   = (int*)base;
    unsigned short* aggb     = (unsigned short*)base;                 // alias of part
    unsigned short* h        = (unsigned short*)(base + (size_t)2 * HC * nN * 4);
    int*            eidx     = (int*)((char*)h + (size_t)nN * IN_F * 2);
    unsigned short* wt       = (unsigned short*)(eidx + nE);
    int*            cnt_in   = (int*)(wt + 128 * 128);
    float*          dinv_out = (float*)(cnt_in + nN);
    float*          dinv_in  = dinv_out + nN;
    int*            offs     = (int*)(dinv_in + nN);
    int*            partscan = offs + nN + 1;

    k_hist    <<<2 * HR * HC, 256, 0, stream>>>(src, dst, part_h, nN, nE);
    k_merge   <<<(nN + 255) / 256, 256, 0, stream>>>(part_h, cnt_in, dinv_out, dinv_in, nN);
    k_scan_blk<<<nb, 256, 0, stream>>>(cnt_in, offs, partscan, nN);
    k_scan_top<<<1, 256, 0, stream>>>(partscan, nb);
    k_scan_add<<<nb, 256, 0, stream>>>(offs, partscan, nN, nE);
    k_scale   <<<(nN * (IN_F / 4) + 255) / 256, 256, 0, stream>>>(feat, dinv_out, h, nN);
    k_wprep   <<<1, 256, 0, stream>>>(W, wt);
    k_bin2    <<<HR * HC, 256, 0, stream>>>(src, dst, offs, part_h + (size_t)HC * nN, eidx, nN, nE);
    k_gather  <<<(nN + 3) / 4, 256, 0, stream>>>(h, eidx, offs, aggb, nN);
    k_gemm    <<<(nN + 63) / 64, 256, 0, stream>>>(aggb, wt, bias, dinv_in, out, nN);
}

// Round 6
// 156.995 us; speedup vs baseline: 1.1927x; 1.1927x over previous
//
#include <hip/hip_runtime.h>

#define IN_F 128
#define HRH 8            // hist node-ranges (LDS 25KB)
#define HCD 64           // dst chunks (= bin chunks, chunkoff table)
#define HCS 32           // src chunks (degree count only)
#define HRB 16           // bin node-ranges (LDS cursor 12.5KB)
#define HIST_RS 6272     // >= ceil(nN/HRH) for nN=50000
#define BIN_RS 3136      // >= ceil(nN/HRB)

typedef __attribute__((ext_vector_type(8))) short bf16x8;
typedef __attribute__((ext_vector_type(4))) float f32x4;

static __device__ __forceinline__ unsigned short f2bf(float x) {
    unsigned u = __float_as_uint(x);
    unsigned r = (u + 0x7FFFu + ((u >> 16) & 1u)) >> 16;
    return (unsigned short)r;
}

// ---------------- privatized histograms: dst (64 chunks) + src (32 chunks) ----
// grid = HRH*HCD + HRH*HCS blocks. No global atomics.
__global__ __launch_bounds__(256) void k_hist(const int* __restrict__ src,
                                              const int* __restrict__ dst,
                                              int* __restrict__ dstpart,
                                              int* __restrict__ srcpart,
                                              int nN, int nE) {
    __shared__ int h[HIST_RS];
    int bid = blockIdx.x;
    const int* key;
    int* part;
    int r, c, nch;
    if (bid < HRH * HCD) {
        key = dst; part = dstpart; nch = HCD;
        r = bid / HCD; c = bid % HCD;
    } else {
        bid -= HRH * HCD;
        key = src; part = srcpart; nch = HCS;
        r = bid / HCS; c = bid % HCS;
    }
    const int rs   = (nN + HRH - 1) / HRH;
    const int rbeg = r * rs;
    const int rsize = min(rs, nN - rbeg);
    if (rsize <= 0) return;

    for (int i = threadIdx.x; i < rsize; i += 256) h[i] = 0;
    __syncthreads();

    const int chunk = (nE + nch - 1) / nch;
    const int ebeg = c * chunk;
    const int eend = min(ebeg + chunk, nE);

    if ((ebeg & 3) == 0) {
        for (int i = ebeg + threadIdx.x * 4; i < eend; i += 256 * 4) {
            if (i + 3 < eend) {
                const int4 k4 = *reinterpret_cast<const int4*>(key + i);
                int a;
                a = k4.x - rbeg; if ((unsigned)a < (unsigned)rsize) atomicAdd(&h[a], 1);
                a = k4.y - rbeg; if ((unsigned)a < (unsigned)rsize) atomicAdd(&h[a], 1);
                a = k4.z - rbeg; if ((unsigned)a < (unsigned)rsize) atomicAdd(&h[a], 1);
                a = k4.w - rbeg; if ((unsigned)a < (unsigned)rsize) atomicAdd(&h[a], 1);
            } else {
                for (int j = i; j < eend; ++j) {
                    int a = key[j] - rbeg;
                    if ((unsigned)a < (unsigned)rsize) atomicAdd(&h[a], 1);
                }
            }
        }
    } else {
        for (int i = ebeg + threadIdx.x; i < eend; i += 256) {
            int a = key[i] - rbeg;
            if ((unsigned)a < (unsigned)rsize) atomicAdd(&h[a], 1);
        }
    }
    __syncthreads();

    int* pout = part + (size_t)c * nN + rbeg;
    for (int i = threadIdx.x; i < rsize; i += 256) pout[i] = h[i];
}

// ---------------- merge: src sums -> dinv_out; dst partials -> per-chunk prefixes
__global__ void k_merge(int* __restrict__ dstpart, const int* __restrict__ srcpart,
                        int* __restrict__ cnt_in,
                        float* __restrict__ dinv_out, float* __restrict__ dinv_in,
                        int nN) {
    const int n = blockIdx.x * blockDim.x + threadIdx.x;
    if (n >= nN) return;
    int s = 0;
#pragma unroll 4
    for (int c = 0; c < HCS; ++c) s += srcpart[(size_t)c * nN + n];
    int run = 0;
#pragma unroll 4
    for (int c = 0; c < HCD; ++c) {
        const size_t idx = (size_t)c * nN + n;
        int v = dstpart[idx];
        dstpart[idx] = run;
        run += v;
    }
    cnt_in[n]   = run;
    dinv_out[n] = rsqrtf(fmaxf((float)s, 1.0f));
    dinv_in[n]  = rsqrtf(fmaxf((float)run, 1.0f));
}

// ---------------- hierarchical exclusive scan: cnt_in -> offs ----------------
__global__ __launch_bounds__(256) void k_scan_blk(const int* __restrict__ cnt,
                                                  int* __restrict__ offs,
                                                  int* __restrict__ part, int nN) {
    __shared__ int ts[256];
    const int t = threadIdx.x;
    const int base = blockIdx.x * 1024 + t * 4;
    int4 v = make_int4(0, 0, 0, 0);
    if (base + 3 < nN) {
        v = *reinterpret_cast<const int4*>(cnt + base);
    } else {
        if (base + 0 < nN) v.x = cnt[base + 0];
        if (base + 1 < nN) v.y = cnt[base + 1];
        if (base + 2 < nN) v.z = cnt[base + 2];
        if (base + 3 < nN) v.w = cnt[base + 3];
    }
    const int s = v.x + v.y + v.z + v.w;
    ts[t] = s;
    __syncthreads();
    for (int d = 1; d < 256; d <<= 1) {
        int u = (t >= d) ? ts[t - d] : 0;
        __syncthreads();
        ts[t] += u;
        __syncthreads();
    }
    const int ex = ts[t] - s;
    if (t == 255) part[blockIdx.x] = ts[255];
    int4 o;
    o.x = ex;
    o.y = o.x + v.x;
    o.z = o.y + v.y;
    o.w = o.z + v.z;
    if (base + 3 < nN) {
        *reinterpret_cast<int4*>(offs + base) = o;
    } else {
        if (base + 0 < nN) offs[base + 0] = o.x;
        if (base + 1 < nN) offs[base + 1] = o.y;
        if (base + 2 < nN) offs[base + 2] = o.z;
        if (base + 3 < nN) offs[base + 3] = o.w;
    }
}

__global__ __launch_bounds__(256) void k_scan_top(int* __restrict__ part, int nb) {
    __shared__ int ts[256];
    const int t = threadIdx.x;
    const int v = (t < nb) ? part[t] : 0;
    ts[t] = v;
    __syncthreads();
    for (int d = 1; d < 256; d <<= 1) {
        int u = (t >= d) ? ts[t - d] : 0;
        __syncthreads();
        ts[t] += u;
        __syncthreads();
    }
    if (t < nb) part[t] = ts[t] - v;
}

__global__ __launch_bounds__(256) void k_scan_add(int* __restrict__ offs,
                                                  const int* __restrict__ part,
                                                  int nN, int nE) {
    const int base = blockIdx.x * 1024 + threadIdx.x * 4;
    const int add = part[blockIdx.x];
    if (base + 3 < nN) {
        int4 o = *reinterpret_cast<int4*>(offs + base);
        o.x += add; o.y += add; o.z += add; o.w += add;
        *reinterpret_cast<int4*>(offs + base) = o;
    } else {
#pragma unroll
        for (int j = 0; j < 4; ++j)
            if (base + j < nN) offs[base + j] += add;
    }
    if (blockIdx.x == 0 && threadIdx.x == 0) offs[nN] = nE;
}

// ---------------- bucket edges by dst via LDS cursors (no global atomics) ----
// grid = HRB * HCD blocks: fine ranges (12.5KB LDS) x chunkoff chunks.
__global__ __launch_bounds__(256) void k_bin2(const int* __restrict__ src,
                                              const int* __restrict__ dst,
                                              const int* __restrict__ offs,
                                              const int* __restrict__ chunkoff,
                                              int* __restrict__ eidx, int nN, int nE) {
    __shared__ int cur[BIN_RS];
    const int bid = blockIdx.x;
    const int r = bid / HCD;
    const int c = bid % HCD;
    const int rs = (nN + HRB - 1) / HRB;
    const int rbeg = r * rs;
    const int rsize = min(rs, nN - rbeg);
    if (rsize <= 0) return;

    for (int i = threadIdx.x; i < rsize; i += 256)
        cur[i] = offs[rbeg + i] + chunkoff[(size_t)c * nN + rbeg + i];
    __syncthreads();

    const int chunk = (nE + HCD - 1) / HCD;
    const int ebeg = c * chunk;
    const int eend = min(ebeg + chunk, nE);
    for (int i = ebeg + threadIdx.x * 4; i < eend; i += 256 * 4) {
        if (i + 3 < eend) {
            const int4 d4 = *reinterpret_cast<const int4*>(dst + i);
            int d;
            d = d4.x - rbeg; if ((unsigned)d < (unsigned)rsize) { int p = atomicAdd(&cur[d], 1); eidx[p] = src[i + 0]; }
            d = d4.y - rbeg; if ((unsigned)d < (unsigned)rsize) { int p = atomicAdd(&cur[d], 1); eidx[p] = src[i + 1]; }
            d = d4.z - rbeg; if ((unsigned)d < (unsigned)rsize) { int p = atomicAdd(&cur[d], 1); eidx[p] = src[i + 2]; }
            d = d4.w - rbeg; if ((unsigned)d < (unsigned)rsize) { int p = atomicAdd(&cur[d], 1); eidx[p] = src[i + 3]; }
        } else {
            for (int j = i; j < eend; ++j) {
                int d = dst[j] - rbeg;
                if ((unsigned)d < (unsigned)rsize) { int p = atomicAdd(&cur[d], 1); eidx[p] = src[j]; }
            }
        }
    }
}

// ---------------- h[n] = bf16(feat[n] * dinv_out[n]) ----------------
__global__ __launch_bounds__(256) void k_scale(const float* __restrict__ feat,
                                               const float* __restrict__ dinv,
                                               unsigned short* __restrict__ h, int nN) {
    const int i = blockIdx.x * 256 + threadIdx.x;  // one thread = 4 elems
    if (i >= nN * (IN_F / 4)) return;
    const int node = i >> 5;
    const int j = (i & 31) * 4;
    const float s = dinv[node];
    const float4 v = *reinterpret_cast<const float4*>(feat + (size_t)node * IN_F + j);
    ushort4 o;
    o.x = f2bf(v.x * s);
    o.y = f2bf(v.y * s);
    o.z = f2bf(v.z * s);
    o.w = f2bf(v.w * s);
    *reinterpret_cast<ushort4*>(h + (size_t)node * IN_F + j) = o;
}

// ---------------- Wt[j][k] = bf16(W[k][j]) (single block) ----------------
__global__ __launch_bounds__(256) void k_wprep(const float* __restrict__ W,
                                               unsigned short* __restrict__ wt) {
    __shared__ float wl[128 * 128];
    for (int i = threadIdx.x * 4; i < 128 * 128; i += 256 * 4)
        *reinterpret_cast<float4*>(&wl[i]) = *reinterpret_cast<const float4*>(&W[i]);
    __syncthreads();
    const int col = threadIdx.x >> 1;
    const int k0  = (threadIdx.x & 1) * 64;
    for (int k = k0; k < k0 + 64; ++k)
        wt[col * 128 + k] = f2bf(wl[k * 128 + col]);
}

// ---------------- gather: agg[d] = bf16( sum_{e in bin(d)} h[src_e] ) ----------
__global__ __launch_bounds__(256) void k_gather(
    const unsigned short* __restrict__ h, const int* __restrict__ eidx,
    const int* __restrict__ offs, unsigned short* __restrict__ agg, int nN) {
    const int node = blockIdx.x * 4 + (threadIdx.x >> 6);
    if (node >= nN) return;
    const int lane = threadIdx.x & 63;
    const int beg = offs[node], end = offs[node + 1];

    float ax = 0.0f, ay = 0.0f;
    for (int base = beg; base < end; base += 64) {
        int n = end - base;
        if (n > 64) n = 64;
        int s_l = 0;
        if (lane < n) s_l = eidx[base + lane];
        for (int i = 0; i < n; ++i) {
            const int s = __shfl(s_l, i);
            const unsigned v = *reinterpret_cast<const unsigned*>(h + (size_t)s * IN_F + lane * 2);
            ax += __uint_as_float(v << 16);
            ay += __uint_as_float(v & 0xFFFF0000u);
        }
    }
    unsigned o = ((unsigned)f2bf(ay) << 16) | (unsigned)f2bf(ax);
    *reinterpret_cast<unsigned*>(agg + (size_t)node * IN_F + lane * 2) = o;
}

// ---------------- out = (agg @ W) * dinv_in[:,None] + bias  (bf16 MFMA) -------
__global__ __launch_bounds__(256) void k_gemm(
    const unsigned short* __restrict__ agg, const unsigned short* __restrict__ wt,
    const float* __restrict__ bias, const float* __restrict__ dinv_in,
    float* __restrict__ out, int nN) {
    const int lane = threadIdx.x & 63;
    const int wave = threadIdx.x >> 6;
    const int r0 = blockIdx.x * 64 + wave * 16;
    const int rA = min(r0 + (lane & 15), nN - 1);
    const int g = lane >> 4;

    float di[4];
#pragma unroll
    for (int q = 0; q < 4; ++q) {
        int rr = r0 + g * 4 + q;
        di[q] = dinv_in[min(rr, nN - 1)];
    }

    f32x4 acc[8];
#pragma unroll
    for (int t = 0; t < 8; ++t) acc[t] = (f32x4){0.f, 0.f, 0.f, 0.f};

#pragma unroll
    for (int s = 0; s < 4; ++s) {
        const bf16x8 a = *reinterpret_cast<const bf16x8*>(agg + (size_t)rA * IN_F + s * 32 + g * 8);
#pragma unroll
        for (int t = 0; t < 8; ++t) {
            const int col = t * 16 + (lane & 15);
            const bf16x8 b = *reinterpret_cast<const bf16x8*>(wt + (size_t)col * IN_F + s * 32 + g * 8);
            acc[t] = __builtin_amdgcn_mfma_f32_16x16x32_bf16(a, b, acc[t], 0, 0, 0);
        }
    }

#pragma unroll
    for (int t = 0; t < 8; ++t) {
        const int col = t * 16 + (lane & 15);
        const float bv = bias[col];
#pragma unroll
        for (int q = 0; q < 4; ++q) {
            const int rr = r0 + g * 4 + q;
            if (rr < nN)
                out[(size_t)rr * IN_F + col] = acc[t][q] * di[q] + bv;
        }
    }
}

extern "C" void kernel_launch(void* const* d_in, const int* in_sizes, int n_in,
                              void* d_out, int out_size, void* d_ws, size_t ws_size,
                              hipStream_t stream) {
    const float* feat = (const float*)d_in[0];
    const int*   src  = (const int*)d_in[1];
    const int*   dst  = (const int*)d_in[2];
    const float* W    = (const float*)d_in[3];
    const float* bias = (const float*)d_in[4];
    float*       out  = (float*)d_out;

    const int nE = in_sizes[1];
    const int nN = in_sizes[0] / IN_F;
    const int nb = (nN + 1023) / 1024;

    // workspace (aliased; ~29.6MB):
    //  [0, 12.8M)        dstpart [HCD][nN] (hist->merge->bin2)   | then h bf16 (scale->gather)
    //  [12.8M, 19.2M)    srcpart [HCS][nN] (hist->merge)         | then agg bf16 spans [12.8M,25.6M) (gather->gemm)
    //  [25.6M, 28.8M)    eidx[nE] (bin2->gather)
    //  tail: wt, cnt_in, dinv_out, dinv_in, offs, partscan
    char* base = (char*)d_ws;
    int*            dstpart  = (int*)base;
    int*            srcpart  = (int*)(base + (size_t)HCD * nN * 4);
    unsigned short* h        = (unsigned short*)base;
    unsigned short* aggb     = (unsigned short*)(base + (size_t)HCD * nN * 4);
    int*            eidx     = (int*)(base + (size_t)HCD * nN * 4 + (size_t)nN * IN_F * 2);
    unsigned short* wt       = (unsigned short*)(eidx + nE);
    int*            cnt_in   = (int*)(wt + 128 * 128);
    float*          dinv_out = (float*)(cnt_in + nN);
    float*          dinv_in  = dinv_out + nN;
    int*            offs     = (int*)(dinv_in + nN);
    int*            partscan = offs + nN + 1;

    k_hist    <<<HRH * (HCD + HCS), 256, 0, stream>>>(src, dst, dstpart, srcpart, nN, nE);
    k_merge   <<<(nN + 255) / 256, 256, 0, stream>>>(dstpart, srcpart, cnt_in, dinv_out, dinv_in, nN);
    k_scan_blk<<<nb, 256, 0, stream>>>(cnt_in, offs, partscan, nN);
    k_scan_top<<<1, 256, 0, stream>>>(partscan, nb);
    k_scan_add<<<nb, 256, 0, stream>>>(offs, partscan, nN, nE);
    k_bin2    <<<HRB * HCD, 256, 0, stream>>>(src, dst, offs, dstpart, eidx, nN, nE);
    k_scale   <<<(nN * (IN_F / 4) + 255) / 256, 256, 0, stream>>>(feat, dinv_out, h, nN);
    k_wprep   <<<1, 256, 0, stream>>>(W, wt);
    k_gather  <<<(nN + 3) / 4, 256, 0, stream>>>(h, eidx, offs, aggb, nN);
    k_gemm    <<<(nN + 63) / 64, 256, 0, stream>>>(aggb, wt, bias, dinv_in, out, nN);
}

// Round 7
// 140.643 us; speedup vs baseline: 1.3314x; 1.1163x over previous
//
#include <hip/hip_runtime.h>

#define IN_F 128
#define HRH 8            // hist node-ranges (LDS 25KB)
#define HCD 64           // dst chunks (= bin chunks, chunkoff table)
#define HCS 32           // src chunks (degree count only)
#define HRB 16           // bin node-ranges (LDS cursor 12.5KB)
#define HIST_RS 6272     // >= ceil(nN/HRH) for nN=50000
#define BIN_RS 3136      // >= ceil(nN/HRB)

typedef __attribute__((ext_vector_type(8))) short bf16x8;
typedef __attribute__((ext_vector_type(4))) float f32x4;

static __device__ __forceinline__ unsigned short f2bf(float x) {
    unsigned u = __float_as_uint(x);
    unsigned r = (u + 0x7FFFu + ((u >> 16) & 1u)) >> 16;
    return (unsigned short)r;
}

// ---------------- privatized histograms: dst (64 chunks) + src (32 chunks) ----
__global__ __launch_bounds__(256) void k_hist(const int* __restrict__ src,
                                              const int* __restrict__ dst,
                                              int* __restrict__ dstpart,
                                              int* __restrict__ srcpart,
                                              int nN, int nE) {
    __shared__ int h[HIST_RS];
    int bid = blockIdx.x;
    const int* key;
    int* part;
    int r, c, nch;
    if (bid < HRH * HCD) {
        key = dst; part = dstpart; nch = HCD;
        r = bid / HCD; c = bid % HCD;
    } else {
        bid -= HRH * HCD;
        key = src; part = srcpart; nch = HCS;
        r = bid / HCS; c = bid % HCS;
    }
    const int rs   = (nN + HRH - 1) / HRH;
    const int rbeg = r * rs;
    const int rsize = min(rs, nN - rbeg);
    if (rsize <= 0) return;

    for (int i = threadIdx.x; i < rsize; i += 256) h[i] = 0;
    __syncthreads();

    const int chunk = (nE + nch - 1) / nch;
    const int ebeg = c * chunk;
    const int eend = min(ebeg + chunk, nE);

    if ((ebeg & 3) == 0) {
        for (int i = ebeg + threadIdx.x * 4; i < eend; i += 256 * 4) {
            if (i + 3 < eend) {
                const int4 k4 = *reinterpret_cast<const int4*>(key + i);
                int a;
                a = k4.x - rbeg; if ((unsigned)a < (unsigned)rsize) atomicAdd(&h[a], 1);
                a = k4.y - rbeg; if ((unsigned)a < (unsigned)rsize) atomicAdd(&h[a], 1);
                a = k4.z - rbeg; if ((unsigned)a < (unsigned)rsize) atomicAdd(&h[a], 1);
                a = k4.w - rbeg; if ((unsigned)a < (unsigned)rsize) atomicAdd(&h[a], 1);
            } else {
                for (int j = i; j < eend; ++j) {
                    int a = key[j] - rbeg;
                    if ((unsigned)a < (unsigned)rsize) atomicAdd(&h[a], 1);
                }
            }
        }
    } else {
        for (int i = ebeg + threadIdx.x; i < eend; i += 256) {
            int a = key[i] - rbeg;
            if ((unsigned)a < (unsigned)rsize) atomicAdd(&h[a], 1);
        }
    }
    __syncthreads();

    int* pout = part + (size_t)c * nN + rbeg;
    for (int i = threadIdx.x; i < rsize; i += 256) pout[i] = h[i];
}

// ---------------- merge: src sums -> dinv_out; dst partials -> per-chunk prefixes
__global__ void k_merge(int* __restrict__ dstpart, const int* __restrict__ srcpart,
                        int* __restrict__ cnt_in,
                        float* __restrict__ dinv_out, float* __restrict__ dinv_in,
                        int nN) {
    const int n = blockIdx.x * blockDim.x + threadIdx.x;
    if (n >= nN) return;
    int s = 0;
#pragma unroll 4
    for (int c = 0; c < HCS; ++c) s += srcpart[(size_t)c * nN + n];
    int run = 0;
#pragma unroll 4
    for (int c = 0; c < HCD; ++c) {
        const size_t idx = (size_t)c * nN + n;
        int v = dstpart[idx];
        dstpart[idx] = run;
        run += v;
    }
    cnt_in[n]   = run;
    dinv_out[n] = rsqrtf(fmaxf((float)s, 1.0f));
    dinv_in[n]  = rsqrtf(fmaxf((float)run, 1.0f));
}

// ---------------- hierarchical exclusive scan: cnt_in -> offs ----------------
__global__ __launch_bounds__(256) void k_scan_blk(const int* __restrict__ cnt,
                                                  int* __restrict__ offs,
                                                  int* __restrict__ part, int nN) {
    __shared__ int ts[256];
    const int t = threadIdx.x;
    const int base = blockIdx.x * 1024 + t * 4;
    int4 v = make_int4(0, 0, 0, 0);
    if (base + 3 < nN) {
        v = *reinterpret_cast<const int4*>(cnt + base);
    } else {
        if (base + 0 < nN) v.x = cnt[base + 0];
        if (base + 1 < nN) v.y = cnt[base + 1];
        if (base + 2 < nN) v.z = cnt[base + 2];
        if (base + 3 < nN) v.w = cnt[base + 3];
    }
    const int s = v.x + v.y + v.z + v.w;
    ts[t] = s;
    __syncthreads();
    for (int d = 1; d < 256; d <<= 1) {
        int u = (t >= d) ? ts[t - d] : 0;
        __syncthreads();
        ts[t] += u;
        __syncthreads();
    }
    const int ex = ts[t] - s;
    if (t == 255) part[blockIdx.x] = ts[255];
    int4 o;
    o.x = ex;
    o.y = o.x + v.x;
    o.z = o.y + v.y;
    o.w = o.z + v.z;
    if (base + 3 < nN) {
        *reinterpret_cast<int4*>(offs + base) = o;
    } else {
        if (base + 0 < nN) offs[base + 0] = o.x;
        if (base + 1 < nN) offs[base + 1] = o.y;
        if (base + 2 < nN) offs[base + 2] = o.z;
        if (base + 3 < nN) offs[base + 3] = o.w;
    }
}

__global__ __launch_bounds__(256) void k_scan_top(int* __restrict__ part, int nb) {
    __shared__ int ts[256];
    const int t = threadIdx.x;
    const int v = (t < nb) ? part[t] : 0;
    ts[t] = v;
    __syncthreads();
    for (int d = 1; d < 256; d <<= 1) {
        int u = (t >= d) ? ts[t - d] : 0;
        __syncthreads();
        ts[t] += u;
        __syncthreads();
    }
    if (t < nb) part[t] = ts[t] - v;
}

__global__ __launch_bounds__(256) void k_scan_add(int* __restrict__ offs,
                                                  const int* __restrict__ part,
                                                  int nN, int nE) {
    const int base = blockIdx.x * 1024 + threadIdx.x * 4;
    const int add = part[blockIdx.x];
    if (base + 3 < nN) {
        int4 o = *reinterpret_cast<int4*>(offs + base);
        o.x += add; o.y += add; o.z += add; o.w += add;
        *reinterpret_cast<int4*>(offs + base) = o;
    } else {
#pragma unroll
        for (int j = 0; j < 4; ++j)
            if (base + j < nN) offs[base + j] += add;
    }
    if (blockIdx.x == 0 && threadIdx.x == 0) offs[nN] = nE;
}

// ---------------- bucket edges by dst via LDS cursors (no global atomics) ----
__global__ __launch_bounds__(256) void k_bin2(const int* __restrict__ src,
                                              const int* __restrict__ dst,
                                              const int* __restrict__ offs,
                                              const int* __restrict__ chunkoff,
                                              int* __restrict__ eidx, int nN, int nE) {
    __shared__ int cur[BIN_RS];
    const int bid = blockIdx.x;
    const int r = bid / HCD;
    const int c = bid % HCD;
    const int rs = (nN + HRB - 1) / HRB;
    const int rbeg = r * rs;
    const int rsize = min(rs, nN - rbeg);
    if (rsize <= 0) return;

    for (int i = threadIdx.x; i < rsize; i += 256)
        cur[i] = offs[rbeg + i] + chunkoff[(size_t)c * nN + rbeg + i];
    __syncthreads();

    const int chunk = (nE + HCD - 1) / HCD;
    const int ebeg = c * chunk;
    const int eend = min(ebeg + chunk, nE);
    for (int i = ebeg + threadIdx.x * 4; i < eend; i += 256 * 4) {
        if (i + 3 < eend) {
            const int4 d4 = *reinterpret_cast<const int4*>(dst + i);
            int d;
            d = d4.x - rbeg; if ((unsigned)d < (unsigned)rsize) { int p = atomicAdd(&cur[d], 1); eidx[p] = src[i + 0]; }
            d = d4.y - rbeg; if ((unsigned)d < (unsigned)rsize) { int p = atomicAdd(&cur[d], 1); eidx[p] = src[i + 1]; }
            d = d4.z - rbeg; if ((unsigned)d < (unsigned)rsize) { int p = atomicAdd(&cur[d], 1); eidx[p] = src[i + 2]; }
            d = d4.w - rbeg; if ((unsigned)d < (unsigned)rsize) { int p = atomicAdd(&cur[d], 1); eidx[p] = src[i + 3]; }
        } else {
            for (int j = i; j < eend; ++j) {
                int d = dst[j] - rbeg;
                if ((unsigned)d < (unsigned)rsize) { int p = atomicAdd(&cur[d], 1); eidx[p] = src[j]; }
            }
        }
    }
}

// ---------------- h[n] = bf16(feat[n] * dinv_out[n]) ----------------
__global__ __launch_bounds__(256) void k_scale(const float* __restrict__ feat,
                                               const float* __restrict__ dinv,
                                               unsigned short* __restrict__ h, int nN) {
    const int i = blockIdx.x * 256 + threadIdx.x;  // one thread = 4 elems
    if (i >= nN * (IN_F / 4)) return;
    const int node = i >> 5;
    const int j = (i & 31) * 4;
    const float s = dinv[node];
    const float4 v = *reinterpret_cast<const float4*>(feat + (size_t)node * IN_F + j);
    ushort4 o;
    o.x = f2bf(v.x * s);
    o.y = f2bf(v.y * s);
    o.z = f2bf(v.z * s);
    o.w = f2bf(v.w * s);
    *reinterpret_cast<ushort4*>(h + (size_t)node * IN_F + j) = o;
}

// ---------------- Wt[j][k] = bf16(W[k][j]) (single block) ----------------
__global__ __launch_bounds__(256) void k_wprep(const float* __restrict__ W,
                                               unsigned short* __restrict__ wt) {
    __shared__ float wl[128 * 128];
    for (int i = threadIdx.x * 4; i < 128 * 128; i += 256 * 4)
        *reinterpret_cast<float4*>(&wl[i]) = *reinterpret_cast<const float4*>(&W[i]);
    __syncthreads();
    const int col = threadIdx.x >> 1;
    const int k0  = (threadIdx.x & 1) * 64;
    for (int k = k0; k < k0 + 64; ++k)
        wt[col * 128 + k] = f2bf(wl[k * 128 + col]);
}

// ---------------- gather: agg[d] = bf16( sum_{e in bin(d)} h[src_e] ) ----------
// one wave per node; lane owns 2 feats. Uniform eidx loads (no shfl),
// hand-unrolled x8: 8 independent scattered loads in flight per batch.
__global__ __launch_bounds__(256) void k_gather(
    const unsigned short* __restrict__ h, const int* __restrict__ eidx,
    const int* __restrict__ offs, unsigned short* __restrict__ agg, int nN) {
    const int node = blockIdx.x * 4 + (threadIdx.x >> 6);
    if (node >= nN) return;
    const int lane = threadIdx.x & 63;
    const int beg = offs[node], end = offs[node + 1];
    const size_t lo = (size_t)(lane * 2);

    float ax = 0.0f, ay = 0.0f;
    int i = beg;
    for (; i + 8 <= end; i += 8) {
        const int s0 = eidx[i + 0], s1 = eidx[i + 1], s2 = eidx[i + 2], s3 = eidx[i + 3];
        const int s4 = eidx[i + 4], s5 = eidx[i + 5], s6 = eidx[i + 6], s7 = eidx[i + 7];
        const unsigned v0 = *reinterpret_cast<const unsigned*>(h + (size_t)s0 * IN_F + lo);
        const unsigned v1 = *reinterpret_cast<const unsigned*>(h + (size_t)s1 * IN_F + lo);
        const unsigned v2 = *reinterpret_cast<const unsigned*>(h + (size_t)s2 * IN_F + lo);
        const unsigned v3 = *reinterpret_cast<const unsigned*>(h + (size_t)s3 * IN_F + lo);
        const unsigned v4 = *reinterpret_cast<const unsigned*>(h + (size_t)s4 * IN_F + lo);
        const unsigned v5 = *reinterpret_cast<const unsigned*>(h + (size_t)s5 * IN_F + lo);
        const unsigned v6 = *reinterpret_cast<const unsigned*>(h + (size_t)s6 * IN_F + lo);
        const unsigned v7 = *reinterpret_cast<const unsigned*>(h + (size_t)s7 * IN_F + lo);
        ax += __uint_as_float(v0 << 16);          ay += __uint_as_float(v0 & 0xFFFF0000u);
        ax += __uint_as_float(v1 << 16);          ay += __uint_as_float(v1 & 0xFFFF0000u);
        ax += __uint_as_float(v2 << 16);          ay += __uint_as_float(v2 & 0xFFFF0000u);
        ax += __uint_as_float(v3 << 16);          ay += __uint_as_float(v3 & 0xFFFF0000u);
        ax += __uint_as_float(v4 << 16);          ay += __uint_as_float(v4 & 0xFFFF0000u);
        ax += __uint_as_float(v5 << 16);          ay += __uint_as_float(v5 & 0xFFFF0000u);
        ax += __uint_as_float(v6 << 16);          ay += __uint_as_float(v6 & 0xFFFF0000u);
        ax += __uint_as_float(v7 << 16);          ay += __uint_as_float(v7 & 0xFFFF0000u);
    }
    for (; i < end; ++i) {
        const int s = eidx[i];
        const unsigned v = *reinterpret_cast<const unsigned*>(h + (size_t)s * IN_F + lo);
        ax += __uint_as_float(v << 16);
        ay += __uint_as_float(v & 0xFFFF0000u);
    }
    unsigned o = ((unsigned)f2bf(ay) << 16) | (unsigned)f2bf(ax);
    *reinterpret_cast<unsigned*>(agg + (size_t)node * IN_F + lo) = o;
}

// ---------------- out = (agg @ W) * dinv_in[:,None] + bias  (bf16 MFMA) -------
__global__ __launch_bounds__(256) void k_gemm(
    const unsigned short* __restrict__ agg, const unsigned short* __restrict__ wt,
    const float* __restrict__ bias, const float* __restrict__ dinv_in,
    float* __restrict__ out, int nN) {
    const int lane = threadIdx.x & 63;
    const int wave = threadIdx.x >> 6;
    const int r0 = blockIdx.x * 64 + wave * 16;
    const int rA = min(r0 + (lane & 15), nN - 1);
    const int g = lane >> 4;

    float di[4];
#pragma unroll
    for (int q = 0; q < 4; ++q) {
        int rr = r0 + g * 4 + q;
        di[q] = dinv_in[min(rr, nN - 1)];
    }

    f32x4 acc[8];
#pragma unroll
    for (int t = 0; t < 8; ++t) acc[t] = (f32x4){0.f, 0.f, 0.f, 0.f};

#pragma unroll
    for (int s = 0; s < 4; ++s) {
        const bf16x8 a = *reinterpret_cast<const bf16x8*>(agg + (size_t)rA * IN_F + s * 32 + g * 8);
#pragma unroll
        for (int t = 0; t < 8; ++t) {
            const int col = t * 16 + (lane & 15);
            const bf16x8 b = *reinterpret_cast<const bf16x8*>(wt + (size_t)col * IN_F + s * 32 + g * 8);
            acc[t] = __builtin_amdgcn_mfma_f32_16x16x32_bf16(a, b, acc[t], 0, 0, 0);
        }
    }

#pragma unroll
    for (int t = 0; t < 8; ++t) {
        const int col = t * 16 + (lane & 15);
        const float bv = bias[col];
#pragma unroll
        for (int q = 0; q < 4; ++q) {
            const int rr = r0 + g * 4 + q;
            if (rr < nN)
                out[(size_t)rr * IN_F + col] = acc[t][q] * di[q] + bv;
        }
    }
}

extern "C" void kernel_launch(void* const* d_in, const int* in_sizes, int n_in,
                              void* d_out, int out_size, void* d_ws, size_t ws_size,
                              hipStream_t stream) {
    const float* feat = (const float*)d_in[0];
    const int*   src  = (const int*)d_in[1];
    const int*   dst  = (const int*)d_in[2];
    const float* W    = (const float*)d_in[3];
    const float* bias = (const float*)d_in[4];
    float*       out  = (float*)d_out;

    const int nE = in_sizes[1];
    const int nN = in_sizes[0] / IN_F;
    const int nb = (nN + 1023) / 1024;

    char* base = (char*)d_ws;
    int*            dstpart  = (int*)base;
    int*            srcpart  = (int*)(base + (size_t)HCD * nN * 4);
    unsigned short* h        = (unsigned short*)base;
    unsigned short* aggb     = (unsigned short*)(base + (size_t)HCD * nN * 4);
    int*            eidx     = (int*)(base + (size_t)HCD * nN * 4 + (size_t)nN * IN_F * 2);
    unsigned short* wt       = (unsigned short*)(eidx + nE);
    int*            cnt_in   = (int*)(wt + 128 * 128);
    float*          dinv_out = (float*)(cnt_in + nN);
    float*          dinv_in  = dinv_out + nN;
    int*            offs     = (int*)(dinv_in + nN);
    int*            partscan = offs + nN + 1;

    k_hist    <<<HRH * (HCD + HCS), 256, 0, stream>>>(src, dst, dstpart, srcpart, nN, nE);
    k_merge   <<<(nN + 255) / 256, 256, 0, stream>>>(dstpart, srcpart, cnt_in, dinv_out, dinv_in, nN);
    k_scan_blk<<<nb, 256, 0, stream>>>(cnt_in, offs, partscan, nN);
    k_scan_top<<<1, 256, 0, stream>>>(partscan, nb);
    k_scan_add<<<nb, 256, 0, stream>>>(offs, partscan, nN, nE);
    k_bin2    <<<HRB * HCD, 256, 0, stream>>>(src, dst, offs, dstpart, eidx, nN, nE);
    k_scale   <<<(nN * (IN_F / 4) + 255) / 256, 256, 0, stream>>>(feat, dinv_out, h, nN);
    k_wprep   <<<1, 256, 0, stream>>>(W, wt);
    k_gather  <<<(nN + 3) / 4, 256, 0, stream>>>(h, eidx, offs, aggb, nN);
    k_gemm    <<<(nN + 63) / 64, 256, 0, stream>>>(aggb, wt, bias, dinv_in, out, nN);
}

// Round 8
// 132.357 us; speedup vs baseline: 1.4147x; 1.0626x over previous
//
#include <hip/hip_runtime.h>

#define IN_F 128
#define HRH 4            // hist node-ranges (LDS 50KB)
#define HCD 64           // dst chunks (= bin chunks, chunkoff table)
#define HCS 32           // src chunks (degree count only)
#define HRB 16           // bin node-ranges (LDS cursor 12.5KB)
#define HIST_RS 12544    // >= ceil(nN/HRH) for nN=50000
#define BIN_RS 3136      // >= ceil(nN/HRB)
#define LROW 68          // LDS tile row stride in uints (272B: conflict-free A-frag reads)

typedef __attribute__((ext_vector_type(8))) short bf16x8;
typedef __attribute__((ext_vector_type(4))) float f32x4;

static __device__ __forceinline__ unsigned short f2bf(float x) {
    unsigned u = __float_as_uint(x);
    unsigned r = (u + 0x7FFFu + ((u >> 16) & 1u)) >> 16;
    return (unsigned short)r;
}

// ---------------- privatized histograms: dst (64 chunks) + src (32 chunks) ----
__global__ __launch_bounds__(256) void k_hist(const int* __restrict__ src,
                                              const int* __restrict__ dst,
                                              int* __restrict__ dstpart,
                                              int* __restrict__ srcpart,
                                              int nN, int nE) {
    __shared__ int h[HIST_RS];
    int bid = blockIdx.x;
    const int* key;
    int* part;
    int r, c, nch;
    if (bid < HRH * HCD) {
        key = dst; part = dstpart; nch = HCD;
        r = bid / HCD; c = bid % HCD;
    } else {
        bid -= HRH * HCD;
        key = src; part = srcpart; nch = HCS;
        r = bid / HCS; c = bid % HCS;
    }
    const int rs   = (nN + HRH - 1) / HRH;
    const int rbeg = r * rs;
    const int rsize = min(rs, nN - rbeg);
    if (rsize <= 0) return;

    for (int i = threadIdx.x; i < rsize; i += 256) h[i] = 0;
    __syncthreads();

    const int chunk = (nE + nch - 1) / nch;
    const int ebeg = c * chunk;
    const int eend = min(ebeg + chunk, nE);

    if ((ebeg & 3) == 0) {
        for (int i = ebeg + threadIdx.x * 4; i < eend; i += 256 * 4) {
            if (i + 3 < eend) {
                const int4 k4 = *reinterpret_cast<const int4*>(key + i);
                int a;
                a = k4.x - rbeg; if ((unsigned)a < (unsigned)rsize) atomicAdd(&h[a], 1);
                a = k4.y - rbeg; if ((unsigned)a < (unsigned)rsize) atomicAdd(&h[a], 1);
                a = k4.z - rbeg; if ((unsigned)a < (unsigned)rsize) atomicAdd(&h[a], 1);
                a = k4.w - rbeg; if ((unsigned)a < (unsigned)rsize) atomicAdd(&h[a], 1);
            } else {
                for (int j = i; j < eend; ++j) {
                    int a = key[j] - rbeg;
                    if ((unsigned)a < (unsigned)rsize) atomicAdd(&h[a], 1);
                }
            }
        }
    } else {
        for (int i = ebeg + threadIdx.x; i < eend; i += 256) {
            int a = key[i] - rbeg;
            if ((unsigned)a < (unsigned)rsize) atomicAdd(&h[a], 1);
        }
    }
    __syncthreads();

    int* pout = part + (size_t)c * nN + rbeg;
    for (int i = threadIdx.x; i < rsize; i += 256) pout[i] = h[i];
}

// ---------------- merge: src sums -> dinv_out; dst partials -> per-chunk prefixes
__global__ void k_merge(int* __restrict__ dstpart, const int* __restrict__ srcpart,
                        int* __restrict__ cnt_in,
                        float* __restrict__ dinv_out, float* __restrict__ dinv_in,
                        int nN) {
    const int n = blockIdx.x * blockDim.x + threadIdx.x;
    if (n >= nN) return;
    int s = 0;
#pragma unroll 4
    for (int c = 0; c < HCS; ++c) s += srcpart[(size_t)c * nN + n];
    int run = 0;
#pragma unroll 4
    for (int c = 0; c < HCD; ++c) {
        const size_t idx = (size_t)c * nN + n;
        int v = dstpart[idx];
        dstpart[idx] = run;
        run += v;
    }
    cnt_in[n]   = run;
    dinv_out[n] = rsqrtf(fmaxf((float)s, 1.0f));
    dinv_in[n]  = rsqrtf(fmaxf((float)run, 1.0f));
}

// ---------------- hierarchical exclusive scan: cnt_in -> offs ----------------
__global__ __launch_bounds__(256) void k_scan_blk(const int* __restrict__ cnt,
                                                  int* __restrict__ offs,
                                                  int* __restrict__ part, int nN) {
    __shared__ int ts[256];
    const int t = threadIdx.x;
    const int base = blockIdx.x * 1024 + t * 4;
    int4 v = make_int4(0, 0, 0, 0);
    if (base + 3 < nN) {
        v = *reinterpret_cast<const int4*>(cnt + base);
    } else {
        if (base + 0 < nN) v.x = cnt[base + 0];
        if (base + 1 < nN) v.y = cnt[base + 1];
        if (base + 2 < nN) v.z = cnt[base + 2];
        if (base + 3 < nN) v.w = cnt[base + 3];
    }
    const int s = v.x + v.y + v.z + v.w;
    ts[t] = s;
    __syncthreads();
    for (int d = 1; d < 256; d <<= 1) {
        int u = (t >= d) ? ts[t - d] : 0;
        __syncthreads();
        ts[t] += u;
        __syncthreads();
    }
    const int ex = ts[t] - s;
    if (t == 255) part[blockIdx.x] = ts[255];
    int4 o;
    o.x = ex;
    o.y = o.x + v.x;
    o.z = o.y + v.y;
    o.w = o.z + v.z;
    if (base + 3 < nN) {
        *reinterpret_cast<int4*>(offs + base) = o;
    } else {
        if (base + 0 < nN) offs[base + 0] = o.x;
        if (base + 1 < nN) offs[base + 1] = o.y;
        if (base + 2 < nN) offs[base + 2] = o.z;
        if (base + 3 < nN) offs[base + 3] = o.w;
    }
}

__global__ __launch_bounds__(256) void k_scan_top(int* __restrict__ part, int nb) {
    __shared__ int ts[256];
    const int t = threadIdx.x;
    const int v = (t < nb) ? part[t] : 0;
    ts[t] = v;
    __syncthreads();
    for (int d = 1; d < 256; d <<= 1) {
        int u = (t >= d) ? ts[t - d] : 0;
        __syncthreads();
        ts[t] += u;
        __syncthreads();
    }
    if (t < nb) part[t] = ts[t] - v;
}

__global__ __launch_bounds__(256) void k_scan_add(int* __restrict__ offs,
                                                  const int* __restrict__ part,
                                                  int nN, int nE) {
    const int base = blockIdx.x * 1024 + threadIdx.x * 4;
    const int add = part[blockIdx.x];
    if (base + 3 < nN) {
        int4 o = *reinterpret_cast<int4*>(offs + base);
        o.x += add; o.y += add; o.z += add; o.w += add;
        *reinterpret_cast<int4*>(offs + base) = o;
    } else {
#pragma unroll
        for (int j = 0; j < 4; ++j)
            if (base + j < nN) offs[base + j] += add;
    }
    if (blockIdx.x == 0 && threadIdx.x == 0) offs[nN] = nE;
}

// ---------------- bucket edges by dst via LDS cursors (no global atomics) ----
__global__ __launch_bounds__(256) void k_bin2(const int* __restrict__ src,
                                              const int* __restrict__ dst,
                                              const int* __restrict__ offs,
                                              const int* __restrict__ chunkoff,
                                              int* __restrict__ eidx, int nN, int nE) {
    __shared__ int cur[BIN_RS];
    const int bid = blockIdx.x;
    const int r = bid / HCD;
    const int c = bid % HCD;
    const int rs = (nN + HRB - 1) / HRB;
    const int rbeg = r * rs;
    const int rsize = min(rs, nN - rbeg);
    if (rsize <= 0) return;

    for (int i = threadIdx.x; i < rsize; i += 256)
        cur[i] = offs[rbeg + i] + chunkoff[(size_t)c * nN + rbeg + i];
    __syncthreads();

    const int chunk = (nE + HCD - 1) / HCD;
    const int ebeg = c * chunk;
    const int eend = min(ebeg + chunk, nE);
    for (int i = ebeg + threadIdx.x * 4; i < eend; i += 256 * 4) {
        if (i + 3 < eend) {
            const int4 d4 = *reinterpret_cast<const int4*>(dst + i);
            int d;
            d = d4.x - rbeg; if ((unsigned)d < (unsigned)rsize) { int p = atomicAdd(&cur[d], 1); eidx[p] = src[i + 0]; }
            d = d4.y - rbeg; if ((unsigned)d < (unsigned)rsize) { int p = atomicAdd(&cur[d], 1); eidx[p] = src[i + 1]; }
            d = d4.z - rbeg; if ((unsigned)d < (unsigned)rsize) { int p = atomicAdd(&cur[d], 1); eidx[p] = src[i + 2]; }
            d = d4.w - rbeg; if ((unsigned)d < (unsigned)rsize) { int p = atomicAdd(&cur[d], 1); eidx[p] = src[i + 3]; }
        } else {
            for (int j = i; j < eend; ++j) {
                int d = dst[j] - rbeg;
                if ((unsigned)d < (unsigned)rsize) { int p = atomicAdd(&cur[d], 1); eidx[p] = src[j]; }
            }
        }
    }
}

// ---------------- h[n] = bf16(feat[n] * dinv_out[n]) ----------------
__global__ __launch_bounds__(256) void k_scale(const float* __restrict__ feat,
                                               const float* __restrict__ dinv,
                                               unsigned short* __restrict__ h, int nN) {
    const int i = blockIdx.x * 256 + threadIdx.x;  // one thread = 4 elems
    if (i >= nN * (IN_F / 4)) return;
    const int node = i >> 5;
    const int j = (i & 31) * 4;
    const float s = dinv[node];
    const float4 v = *reinterpret_cast<const float4*>(feat + (size_t)node * IN_F + j);
    ushort4 o;
    o.x = f2bf(v.x * s);
    o.y = f2bf(v.y * s);
    o.z = f2bf(v.z * s);
    o.w = f2bf(v.w * s);
    *reinterpret_cast<ushort4*>(h + (size_t)node * IN_F + j) = o;
}

// ---------------- Wt[j][k] = bf16(W[k][j]) (single block) ----------------
__global__ __launch_bounds__(256) void k_wprep(const float* __restrict__ W,
                                               unsigned short* __restrict__ wt) {
    __shared__ float wl[128 * 128];
    for (int i = threadIdx.x * 4; i < 128 * 128; i += 256 * 4)
        *reinterpret_cast<float4*>(&wl[i]) = *reinterpret_cast<const float4*>(&W[i]);
    __syncthreads();
    const int col = threadIdx.x >> 1;
    const int k0  = (threadIdx.x & 1) * 64;
    for (int k = k0; k < k0 + 64; ++k)
        wt[col * 128 + k] = f2bf(wl[k * 128 + col]);
}

// ---------------- fused gather + GEMM ----------------
// block = 4 waves = 16 nodes. Phase 1: wave w gathers rows w*4..w*4+3 into a
// padded LDS tile (stride LROW=68 uints = 272B -> even 32-bank coverage for
// the A-frag ds_read_b128s). Phase 2: 16x128 tile x W via MFMA; epilogue
// applies dinv_in + bias.
__global__ __launch_bounds__(256) void k_gg(
    const unsigned short* __restrict__ h, const int* __restrict__ eidx,
    const int* __restrict__ offs, const unsigned short* __restrict__ wt,
    const float* __restrict__ bias, const float* __restrict__ dinv_in,
    float* __restrict__ out, int nN) {
    __shared__ unsigned tile[16 * LROW];
    const int lane = threadIdx.x & 63;
    const int wave = threadIdx.x >> 6;
    const int blk16 = blockIdx.x * 16;
    const size_t lo = (size_t)(lane * 2);

    // ---- phase 1: gather 4 node rows per wave ----
    for (int j = 0; j < 4; ++j) {
        const int trow = wave * 4 + j;
        const int node = blk16 + trow;
        float ax = 0.0f, ay = 0.0f;
        if (node < nN) {
            const int beg = offs[node], end = offs[node + 1];
            int i = beg;
            for (; i + 8 <= end; i += 8) {
                const int s0 = eidx[i + 0], s1 = eidx[i + 1], s2 = eidx[i + 2], s3 = eidx[i + 3];
                const int s4 = eidx[i + 4], s5 = eidx[i + 5], s6 = eidx[i + 6], s7 = eidx[i + 7];
                const unsigned v0 = *reinterpret_cast<const unsigned*>(h + (size_t)s0 * IN_F + lo);
                const unsigned v1 = *reinterpret_cast<const unsigned*>(h + (size_t)s1 * IN_F + lo);
                const unsigned v2 = *reinterpret_cast<const unsigned*>(h + (size_t)s2 * IN_F + lo);
                const unsigned v3 = *reinterpret_cast<const unsigned*>(h + (size_t)s3 * IN_F + lo);
                const unsigned v4 = *reinterpret_cast<const unsigned*>(h + (size_t)s4 * IN_F + lo);
                const unsigned v5 = *reinterpret_cast<const unsigned*>(h + (size_t)s5 * IN_F + lo);
                const unsigned v6 = *reinterpret_cast<const unsigned*>(h + (size_t)s6 * IN_F + lo);
                const unsigned v7 = *reinterpret_cast<const unsigned*>(h + (size_t)s7 * IN_F + lo);
                ax += __uint_as_float(v0 << 16);          ay += __uint_as_float(v0 & 0xFFFF0000u);
                ax += __uint_as_float(v1 << 16);          ay += __uint_as_float(v1 & 0xFFFF0000u);
                ax += __uint_as_float(v2 << 16);          ay += __uint_as_float(v2 & 0xFFFF0000u);
                ax += __uint_as_float(v3 << 16);          ay += __uint_as_float(v3 & 0xFFFF0000u);
                ax += __uint_as_float(v4 << 16);          ay += __uint_as_float(v4 & 0xFFFF0000u);
                ax += __uint_as_float(v5 << 16);          ay += __uint_as_float(v5 & 0xFFFF0000u);
                ax += __uint_as_float(v6 << 16);          ay += __uint_as_float(v6 & 0xFFFF0000u);
                ax += __uint_as_float(v7 << 16);          ay += __uint_as_float(v7 & 0xFFFF0000u);
            }
            for (; i < end; ++i) {
                const int s = eidx[i];
                const unsigned v = *reinterpret_cast<const unsigned*>(h + (size_t)s * IN_F + lo);
                ax += __uint_as_float(v << 16);
                ay += __uint_as_float(v & 0xFFFF0000u);
            }
        }
        tile[trow * LROW + lane] = ((unsigned)f2bf(ay) << 16) | (unsigned)f2bf(ax);
    }
    __syncthreads();

    // ---- phase 2: [16 x 128] @ W  (2 col-tiles per wave) ----
    const int g = lane >> 4;       // k-group / C-row group
    const int cl = lane & 15;      // col-in-tile / A-row

    float di[4];
#pragma unroll
    for (int q = 0; q < 4; ++q)
        di[q] = dinv_in[min(blk16 + g * 4 + q, nN - 1)];

    f32x4 acc0 = (f32x4){0.f, 0.f, 0.f, 0.f};
    f32x4 acc1 = (f32x4){0.f, 0.f, 0.f, 0.f};
    const int col0 = wave * 16 + cl;
    const int col1 = (wave + 4) * 16 + cl;

#pragma unroll
    for (int s = 0; s < 4; ++s) {
        const bf16x8 a = *reinterpret_cast<const bf16x8*>(tile + cl * LROW + s * 16 + g * 4);
        const bf16x8 b0 = *reinterpret_cast<const bf16x8*>(wt + (size_t)col0 * IN_F + s * 32 + g * 8);
        const bf16x8 b1 = *reinterpret_cast<const bf16x8*>(wt + (size_t)col1 * IN_F + s * 32 + g * 8);
        acc0 = __builtin_amdgcn_mfma_f32_16x16x32_bf16(a, b0, acc0, 0, 0, 0);
        acc1 = __builtin_amdgcn_mfma_f32_16x16x32_bf16(a, b1, acc1, 0, 0, 0);
    }

    const float bv0 = bias[col0];
    const float bv1 = bias[col1];
#pragma unroll
    for (int q = 0; q < 4; ++q) {
        const int rr = blk16 + g * 4 + q;
        if (rr < nN) {
            out[(size_t)rr * IN_F + col0] = acc0[q] * di[q] + bv0;
            out[(size_t)rr * IN_F + col1] = acc1[q] * di[q] + bv1;
        }
    }
}

extern "C" void kernel_launch(void* const* d_in, const int* in_sizes, int n_in,
                              void* d_out, int out_size, void* d_ws, size_t ws_size,
                              hipStream_t stream) {
    const float* feat = (const float*)d_in[0];
    const int*   src  = (const int*)d_in[1];
    const int*   dst  = (const int*)d_in[2];
    const float* W    = (const float*)d_in[3];
    const float* bias = (const float*)d_in[4];
    float*       out  = (float*)d_out;

    const int nE = in_sizes[1];
    const int nN = in_sizes[0] / IN_F;
    const int nb = (nN + 1023) / 1024;

    // workspace (aliased):
    //  [0, 12.8M)      dstpart [HCD][nN] (hist->merge->bin2) | then h bf16 (scale->gg)
    //  [12.8M, 19.2M)  srcpart [HCS][nN] (hist->merge)
    //  [25.6M, 28.8M)  eidx[nE] (bin2->gg)
    //  tail: wt, cnt_in, dinv_out, dinv_in, offs, partscan
    char* base = (char*)d_ws;
    int*            dstpart  = (int*)base;
    int*            srcpart  = (int*)(base + (size_t)HCD * nN * 4);
    unsigned short* h        = (unsigned short*)base;
    int*            eidx     = (int*)(base + (size_t)HCD * nN * 4 + (size_t)nN * IN_F * 2);
    unsigned short* wt       = (unsigned short*)(eidx + nE);
    int*            cnt_in   = (int*)(wt + 128 * 128);
    float*          dinv_out = (float*)(cnt_in + nN);
    float*          dinv_in  = dinv_out + nN;
    int*            offs     = (int*)(dinv_in + nN);
    int*            partscan = offs + nN + 1;

    k_hist    <<<HRH * (HCD + HCS), 256, 0, stream>>>(src, dst, dstpart, srcpart, nN, nE);
    k_merge   <<<(nN + 255) / 256, 256, 0, stream>>>(dstpart, srcpart, cnt_in, dinv_out, dinv_in, nN);
    k_scan_blk<<<nb, 256, 0, stream>>>(cnt_in, offs, partscan, nN);
    k_scan_top<<<1, 256, 0, stream>>>(partscan, nb);
    k_scan_add<<<nb, 256, 0, stream>>>(offs, partscan, nN, nE);
    k_bin2    <<<HRB * HCD, 256, 0, stream>>>(src, dst, offs, dstpart, eidx, nN, nE);
    k_scale   <<<(nN * (IN_F / 4) + 255) / 256, 256, 0, stream>>>(feat, dinv_out, h, nN);
    k_wprep   <<<1, 256, 0, stream>>>(W, wt);
    k_gg      <<<(nN + 15) / 16, 256, 0, stream>>>(h, eidx, offs, wt, bias, dinv_in, out, nN);
}

// Round 9
// 121.299 us; speedup vs baseline: 1.5437x; 1.0912x over previous
//
#include <hip/hip_runtime.h>

#define IN_F 128
#define HRH 4            // hist node-ranges (LDS 50KB)
#define HCD 64           // dst chunks (= bin chunks, chunkoff table)
#define HCS 32           // src chunks (degree count only)
#define HRB 8            // bin node-ranges (LDS cursor 25KB)
#define HIST_RS 12544    // >= ceil(nN/HRH) for nN=50000
#define BIN_RS 6272      // >= ceil(nN/HRB)
#define LROW 68          // LDS tile row stride in uints (272B: conflict-free A-frag reads)

typedef __attribute__((ext_vector_type(8))) short bf16x8;
typedef __attribute__((ext_vector_type(4))) float f32x4;

static __device__ __forceinline__ unsigned short f2bf(float x) {
    unsigned u = __float_as_uint(x);
    unsigned r = (u + 0x7FFFu + ((u >> 16) & 1u)) >> 16;
    return (unsigned short)r;
}

// ---------------- privatized histograms: dst (64 chunks) + src (32 chunks) ----
__global__ __launch_bounds__(256) void k_hist(const int* __restrict__ src,
                                              const int* __restrict__ dst,
                                              int* __restrict__ dstpart,
                                              int* __restrict__ srcpart,
                                              int nN, int nE) {
    __shared__ int h[HIST_RS];
    int bid = blockIdx.x;
    const int* key;
    int* part;
    int r, c, nch;
    if (bid < HRH * HCD) {
        key = dst; part = dstpart; nch = HCD;
        r = bid / HCD; c = bid % HCD;
    } else {
        bid -= HRH * HCD;
        key = src; part = srcpart; nch = HCS;
        r = bid / HCS; c = bid % HCS;
    }
    const int rs   = (nN + HRH - 1) / HRH;
    const int rbeg = r * rs;
    const int rsize = min(rs, nN - rbeg);
    if (rsize <= 0) return;

    for (int i = threadIdx.x; i < rsize; i += 256) h[i] = 0;
    __syncthreads();

    const int chunk = (nE + nch - 1) / nch;
    const int ebeg = c * chunk;
    const int eend = min(ebeg + chunk, nE);

    if ((ebeg & 3) == 0) {
        for (int i = ebeg + threadIdx.x * 4; i < eend; i += 256 * 4) {
            if (i + 3 < eend) {
                const int4 k4 = *reinterpret_cast<const int4*>(key + i);
                int a;
                a = k4.x - rbeg; if ((unsigned)a < (unsigned)rsize) atomicAdd(&h[a], 1);
                a = k4.y - rbeg; if ((unsigned)a < (unsigned)rsize) atomicAdd(&h[a], 1);
                a = k4.z - rbeg; if ((unsigned)a < (unsigned)rsize) atomicAdd(&h[a], 1);
                a = k4.w - rbeg; if ((unsigned)a < (unsigned)rsize) atomicAdd(&h[a], 1);
            } else {
                for (int j = i; j < eend; ++j) {
                    int a = key[j] - rbeg;
                    if ((unsigned)a < (unsigned)rsize) atomicAdd(&h[a], 1);
                }
            }
        }
    } else {
        for (int i = ebeg + threadIdx.x; i < eend; i += 256) {
            int a = key[i] - rbeg;
            if ((unsigned)a < (unsigned)rsize) atomicAdd(&h[a], 1);
        }
    }
    __syncthreads();

    int* pout = part + (size_t)c * nN + rbeg;
    for (int i = threadIdx.x; i < rsize; i += 256) pout[i] = h[i];
}

// ---------------- merge: src sums -> dinv_out; dst partials -> per-chunk prefixes
// emits PADDED count (roundup8) for the scan, real count for pad-fill/dinv_in.
__global__ void k_merge(int* __restrict__ dstpart, const int* __restrict__ srcpart,
                        int* __restrict__ cnt_pad, int* __restrict__ creal,
                        float* __restrict__ dinv_out, float* __restrict__ dinv_in,
                        int nN) {
    const int n = blockIdx.x * blockDim.x + threadIdx.x;
    if (n > nN) return;
    if (n == nN) { cnt_pad[n] = 0; return; }   // scan sentinel slot
    int s = 0;
#pragma unroll 4
    for (int c = 0; c < HCS; ++c) s += srcpart[(size_t)c * nN + n];
    int run = 0;
#pragma unroll 4
    for (int c = 0; c < HCD; ++c) {
        const size_t idx = (size_t)c * nN + n;
        int v = dstpart[idx];
        dstpart[idx] = run;
        run += v;
    }
    cnt_pad[n]  = (run + 7) & ~7;
    creal[n]    = run;
    dinv_out[n] = rsqrtf(fmaxf((float)s, 1.0f));
    dinv_in[n]  = rsqrtf(fmaxf((float)run, 1.0f));
}

// ---------------- hierarchical exclusive scan over nNs = nN+1 elements -------
__global__ __launch_bounds__(256) void k_scan_blk(const int* __restrict__ cnt,
                                                  int* __restrict__ offs,
                                                  int* __restrict__ part, int nNs) {
    __shared__ int ts[256];
    const int t = threadIdx.x;
    const int base = blockIdx.x * 1024 + t * 4;
    int4 v = make_int4(0, 0, 0, 0);
    if (base + 3 < nNs) {
        v = *reinterpret_cast<const int4*>(cnt + base);
    } else {
        if (base + 0 < nNs) v.x = cnt[base + 0];
        if (base + 1 < nNs) v.y = cnt[base + 1];
        if (base + 2 < nNs) v.z = cnt[base + 2];
        if (base + 3 < nNs) v.w = cnt[base + 3];
    }
    const int s = v.x + v.y + v.z + v.w;
    ts[t] = s;
    __syncthreads();
    for (int d = 1; d < 256; d <<= 1) {
        int u = (t >= d) ? ts[t - d] : 0;
        __syncthreads();
        ts[t] += u;
        __syncthreads();
    }
    const int ex = ts[t] - s;
    if (t == 255) part[blockIdx.x] = ts[255];
    int4 o;
    o.x = ex;
    o.y = o.x + v.x;
    o.z = o.y + v.y;
    o.w = o.z + v.z;
    if (base + 3 < nNs) {
        *reinterpret_cast<int4*>(offs + base) = o;
    } else {
        if (base + 0 < nNs) offs[base + 0] = o.x;
        if (base + 1 < nNs) offs[base + 1] = o.y;
        if (base + 2 < nNs) offs[base + 2] = o.z;
        if (base + 3 < nNs) offs[base + 3] = o.w;
    }
}

__global__ __launch_bounds__(256) void k_scan_top(int* __restrict__ part, int nb) {
    __shared__ int ts[256];
    const int t = threadIdx.x;
    const int v = (t < nb) ? part[t] : 0;
    ts[t] = v;
    __syncthreads();
    for (int d = 1; d < 256; d <<= 1) {
        int u = (t >= d) ? ts[t - d] : 0;
        __syncthreads();
        ts[t] += u;
        __syncthreads();
    }
    if (t < nb) part[t] = ts[t] - v;
}

__global__ __launch_bounds__(256) void k_scan_add(int* __restrict__ offs,
                                                  const int* __restrict__ part,
                                                  int nNs) {
    const int base = blockIdx.x * 1024 + threadIdx.x * 4;
    const int add = part[blockIdx.x];
    if (base + 3 < nNs) {
        int4 o = *reinterpret_cast<int4*>(offs + base);
        o.x += add; o.y += add; o.z += add; o.w += add;
        *reinterpret_cast<int4*>(offs + base) = o;
    } else {
#pragma unroll
        for (int j = 0; j < 4; ++j)
            if (base + j < nNs) offs[base + j] += add;
    }
}

// ---------------- fill pad slots with the zero-row index nN ----------------
__global__ void k_pad(const int* __restrict__ offs, const int* __restrict__ creal,
                      int* __restrict__ eidx, int nN) {
    const int n = blockIdx.x * blockDim.x + threadIdx.x;
    if (n >= nN) return;
    const int s = offs[n] + creal[n];
    const int e = offs[n + 1];
    for (int i = s; i < e; ++i) eidx[i] = nN;
}

// ---------------- bucket edges by dst via LDS cursors (no global atomics) ----
__global__ __launch_bounds__(256) void k_bin2(const int* __restrict__ src,
                                              const int* __restrict__ dst,
                                              const int* __restrict__ offs,
                                              const int* __restrict__ chunkoff,
                                              int* __restrict__ eidx, int nN, int nE) {
    __shared__ int cur[BIN_RS];
    const int bid = blockIdx.x;
    const int r = bid / HCD;
    const int c = bid % HCD;
    const int rs = (nN + HRB - 1) / HRB;
    const int rbeg = r * rs;
    const int rsize = min(rs, nN - rbeg);
    if (rsize <= 0) return;

    for (int i = threadIdx.x; i < rsize; i += 256)
        cur[i] = offs[rbeg + i] + chunkoff[(size_t)c * nN + rbeg + i];
    __syncthreads();

    const int chunk = (nE + HCD - 1) / HCD;
    const int ebeg = c * chunk;
    const int eend = min(ebeg + chunk, nE);
    for (int i = ebeg + threadIdx.x * 4; i < eend; i += 256 * 4) {
        if (i + 3 < eend) {
            const int4 d4 = *reinterpret_cast<const int4*>(dst + i);
            int d;
            d = d4.x - rbeg; if ((unsigned)d < (unsigned)rsize) { int p = atomicAdd(&cur[d], 1); eidx[p] = src[i + 0]; }
            d = d4.y - rbeg; if ((unsigned)d < (unsigned)rsize) { int p = atomicAdd(&cur[d], 1); eidx[p] = src[i + 1]; }
            d = d4.z - rbeg; if ((unsigned)d < (unsigned)rsize) { int p = atomicAdd(&cur[d], 1); eidx[p] = src[i + 2]; }
            d = d4.w - rbeg; if ((unsigned)d < (unsigned)rsize) { int p = atomicAdd(&cur[d], 1); eidx[p] = src[i + 3]; }
        } else {
            for (int j = i; j < eend; ++j) {
                int d = dst[j] - rbeg;
                if ((unsigned)d < (unsigned)rsize) { int p = atomicAdd(&cur[d], 1); eidx[p] = src[j]; }
            }
        }
    }
}

// ---------------- h[n] = bf16(feat[n] * dinv_out[n]); row nN = zeros ----------
__global__ __launch_bounds__(256) void k_scale(const float* __restrict__ feat,
                                               const float* __restrict__ dinv,
                                               unsigned short* __restrict__ h, int nN) {
    const int i = blockIdx.x * 256 + threadIdx.x;  // one thread = 4 elems
    if (i >= (nN + 1) * (IN_F / 4)) return;
    const int node = i >> 5;
    const int j = (i & 31) * 4;
    ushort4 o = make_ushort4(0, 0, 0, 0);
    if (node < nN) {
        const float s = dinv[node];
        const float4 v = *reinterpret_cast<const float4*>(feat + (size_t)node * IN_F + j);
        o.x = f2bf(v.x * s);
        o.y = f2bf(v.y * s);
        o.z = f2bf(v.z * s);
        o.w = f2bf(v.w * s);
    }
    *reinterpret_cast<ushort4*>(h + (size_t)node * IN_F + j) = o;
}

// ---------------- Wt[j][k] = bf16(W[k][j]) (single block) ----------------
__global__ __launch_bounds__(256) void k_wprep(const float* __restrict__ W,
                                               unsigned short* __restrict__ wt) {
    __shared__ float wl[128 * 128];
    for (int i = threadIdx.x * 4; i < 128 * 128; i += 256 * 4)
        *reinterpret_cast<float4*>(&wl[i]) = *reinterpret_cast<const float4*>(&W[i]);
    __syncthreads();
    const int col = threadIdx.x >> 1;
    const int k0  = (threadIdx.x & 1) * 64;
    for (int k = k0; k < k0 + 64; ++k)
        wt[col * 128 + k] = f2bf(wl[k * 128 + col]);
}

// ---------------- fused gather + GEMM ----------------
// block = 4 waves = 16 nodes. Phase 1: pipelined gather — bins are padded to
// x8 with the zero row, eidx for batch i+1 prefetched while batch i's h-loads
// are in flight (one memory round-trip per batch). Phase 2: 16x128 @ W MFMA.
__global__ __launch_bounds__(256) void k_gg(
    const unsigned short* __restrict__ h, const int* __restrict__ eidx,
    const int* __restrict__ offs, const unsigned short* __restrict__ wt,
    const float* __restrict__ bias, const float* __restrict__ dinv_in,
    float* __restrict__ out, int nN) {
    __shared__ unsigned tile[16 * LROW];
    const int lane = threadIdx.x & 63;
    const int wave = threadIdx.x >> 6;
    const int blk16 = blockIdx.x * 16;
    const size_t lo = (size_t)(lane * 2);

    // ---- phase 1: gather 4 node rows per wave ----
    for (int j = 0; j < 4; ++j) {
        const int trow = wave * 4 + j;
        const int node = blk16 + trow;
        float ax = 0.0f, ay = 0.0f;
        if (node < nN) {
            const int beg = offs[node], end = offs[node + 1];
            if (beg < end) {
                int4 ea = *reinterpret_cast<const int4*>(eidx + beg);
                int4 eb = *reinterpret_cast<const int4*>(eidx + beg + 4);
                for (int i = beg; i < end; i += 8) {
                    const int s0 = ea.x, s1 = ea.y, s2 = ea.z, s3 = ea.w;
                    const int s4 = eb.x, s5 = eb.y, s6 = eb.z, s7 = eb.w;
                    const unsigned v0 = *reinterpret_cast<const unsigned*>(h + (size_t)s0 * IN_F + lo);
                    const unsigned v1 = *reinterpret_cast<const unsigned*>(h + (size_t)s1 * IN_F + lo);
                    const unsigned v2 = *reinterpret_cast<const unsigned*>(h + (size_t)s2 * IN_F + lo);
                    const unsigned v3 = *reinterpret_cast<const unsigned*>(h + (size_t)s3 * IN_F + lo);
                    const unsigned v4 = *reinterpret_cast<const unsigned*>(h + (size_t)s4 * IN_F + lo);
                    const unsigned v5 = *reinterpret_cast<const unsigned*>(h + (size_t)s5 * IN_F + lo);
                    const unsigned v6 = *reinterpret_cast<const unsigned*>(h + (size_t)s6 * IN_F + lo);
                    const unsigned v7 = *reinterpret_cast<const unsigned*>(h + (size_t)s7 * IN_F + lo);
                    if (i + 8 < end) {  // prefetch next batch's indices (wave-uniform branch)
                        ea = *reinterpret_cast<const int4*>(eidx + i + 8);
                        eb = *reinterpret_cast<const int4*>(eidx + i + 12);
                    }
                    ax += __uint_as_float(v0 << 16);          ay += __uint_as_float(v0 & 0xFFFF0000u);
                    ax += __uint_as_float(v1 << 16);          ay += __uint_as_float(v1 & 0xFFFF0000u);
                    ax += __uint_as_float(v2 << 16);          ay += __uint_as_float(v2 & 0xFFFF0000u);
                    ax += __uint_as_float(v3 << 16);          ay += __uint_as_float(v3 & 0xFFFF0000u);
                    ax += __uint_as_float(v4 << 16);          ay += __uint_as_float(v4 & 0xFFFF0000u);
                    ax += __uint_as_float(v5 << 16);          ay += __uint_as_float(v5 & 0xFFFF0000u);
                    ax += __uint_as_float(v6 << 16);          ay += __uint_as_float(v6 & 0xFFFF0000u);
                    ax += __uint_as_float(v7 << 16);          ay += __uint_as_float(v7 & 0xFFFF0000u);
                }
            }
        }
        tile[trow * LROW + lane] = ((unsigned)f2bf(ay) << 16) | (unsigned)f2bf(ax);
    }
    __syncthreads();

    // ---- phase 2: [16 x 128] @ W  (2 col-tiles per wave) ----
    const int g = lane >> 4;       // k-group / C-row group
    const int cl = lane & 15;      // col-in-tile / A-row

    float di[4];
#pragma unroll
    for (int q = 0; q < 4; ++q)
        di[q] = dinv_in[min(blk16 + g * 4 + q, nN - 1)];

    f32x4 acc0 = (f32x4){0.f, 0.f, 0.f, 0.f};
    f32x4 acc1 = (f32x4){0.f, 0.f, 0.f, 0.f};
    const int col0 = wave * 16 + cl;
    const int col1 = (wave + 4) * 16 + cl;

#pragma unroll
    for (int s = 0; s < 4; ++s) {
        const bf16x8 a = *reinterpret_cast<const bf16x8*>(tile + cl * LROW + s * 16 + g * 4);
        const bf16x8 b0 = *reinterpret_cast<const bf16x8*>(wt + (size_t)col0 * IN_F + s * 32 + g * 8);
        const bf16x8 b1 = *reinterpret_cast<const bf16x8*>(wt + (size_t)col1 * IN_F + s * 32 + g * 8);
        acc0 = __builtin_amdgcn_mfma_f32_16x16x32_bf16(a, b0, acc0, 0, 0, 0);
        acc1 = __builtin_amdgcn_mfma_f32_16x16x32_bf16(a, b1, acc1, 0, 0, 0);
    }

    const float bv0 = bias[col0];
    const float bv1 = bias[col1];
#pragma unroll
    for (int q = 0; q < 4; ++q) {
        const int rr = blk16 + g * 4 + q;
        if (rr < nN) {
            out[(size_t)rr * IN_F + col0] = acc0[q] * di[q] + bv0;
            out[(size_t)rr * IN_F + col1] = acc1[q] * di[q] + bv1;
        }
    }
}

extern "C" void kernel_launch(void* const* d_in, const int* in_sizes, int n_in,
                              void* d_out, int out_size, void* d_ws, size_t ws_size,
                              hipStream_t stream) {
    const float* feat = (const float*)d_in[0];
    const int*   src  = (const int*)d_in[1];
    const int*   dst  = (const int*)d_in[2];
    const float* W    = (const float*)d_in[3];
    const float* bias = (const float*)d_in[4];
    float*       out  = (float*)d_out;

    const int nE = in_sizes[1];
    const int nN = in_sizes[0] / IN_F;
    const int nNs = nN + 1;                 // scan length (sentinel slot)
    const int nb = (nNs + 1023) / 1024;

    // workspace (aliased, ~25MB):
    //  [0, 12.8M)          dstpart [HCD][nN] (hist->merge->bin2) | then h bf16 (nN+1 rows, scale->gg)
    //  [12.8M, 19.2M)      srcpart [HCS][nN] (hist->merge); h's zero row overlaps first 256B (dead by then)
    //  [19.2M, ~23.8M)     eidx padded (bin2/pad->gg)
    //  tail: wt, cnt_pad, creal, dinv_out, dinv_in, offs, partscan
    char* base = (char*)d_ws;
    int*            dstpart  = (int*)base;
    int*            srcpart  = (int*)(base + (size_t)HCD * nN * 4);
    unsigned short* h        = (unsigned short*)base;
    int*            eidx     = (int*)(base + (size_t)(HCD + HCS) * nN * 4);
    int*            eidx_end = eidx + nE + 8 * nN;  // capacity bound
    unsigned short* wt       = (unsigned short*)eidx_end;
    int*            cnt_pad  = (int*)(wt + 128 * 128);
    int*            creal    = cnt_pad + nNs + 4;
    float*          dinv_out = (float*)(creal + nN + 4);
    float*          dinv_in  = dinv_out + nN;
    int*            offs     = (int*)(dinv_in + nN);
    int*            partscan = offs + nNs + 4;

    k_hist    <<<HRH * (HCD + HCS), 256, 0, stream>>>(src, dst, dstpart, srcpart, nN, nE);
    k_merge   <<<(nNs + 255) / 256, 256, 0, stream>>>(dstpart, srcpart, cnt_pad, creal, dinv_out, dinv_in, nN);
    k_scan_blk<<<nb, 256, 0, stream>>>(cnt_pad, offs, partscan, nNs);
    k_scan_top<<<1, 256, 0, stream>>>(partscan, nb);
    k_scan_add<<<nb, 256, 0, stream>>>(offs, partscan, nNs);
    k_pad     <<<(nN + 255) / 256, 256, 0, stream>>>(offs, creal, eidx, nN);
    k_bin2    <<<HRB * HCD, 256, 0, stream>>>(src, dst, offs, dstpart, eidx, nN, nE);
    k_scale   <<<((nN + 1) * (IN_F / 4) + 255) / 256, 256, 0, stream>>>(feat, dinv_out, h, nN);
    k_wprep   <<<1, 256, 0, stream>>>(W, wt);
    k_gg      <<<(nN + 15) / 16, 256, 0, stream>>>(h, eidx, offs, wt, bias, dinv_in, out, nN);
}